// Round 4
// baseline (3702.755 us; speedup 1.0000x reference)
//
#include <hip/hip_runtime.h>
#include <hip/hip_bf16.h>
#include <cmath>

typedef __hip_bfloat16 bf16;

__device__ __forceinline__ float b2f(bf16 x) { return __bfloat162float(x); }
__device__ __forceinline__ float ldf(const void* p, long long i, int f32) {
    return f32 ? ((const float*)p)[i] : b2f(((const bf16*)p)[i]);
}

// A-storage helpers (fp32 primary mode, bf16 fallback if ws_size is small)
__device__ __forceinline__ float ldA(const float* p, long long i) { return p[i]; }
__device__ __forceinline__ float ldA(const bf16* p, long long i)  { return b2f(p[i]); }
__device__ __forceinline__ void  stA(float* p, long long i, float v) { p[i] = v; }
__device__ __forceinline__ void  stA(bf16* p, long long i, float v)  { p[i] = __float2bfloat16(v); }

#define RR 8  // endmembers

// flags: [0]=X f32? [1]=M0 [2]=A0 [3]=Wa [4]=lambd [5]=L [6]=L2 [7]=p
//        [8]=alpha [9]=tau [10]=H [11]=W
// sc: [0]=Lk [1]=alpha [2]=pk [3]=lmbda(prox) [4]=inv8 [5]=L2k

// ---------------------------------------------------------------------------
__global__ void k_probe(
    const void* X, long long nX, const void* M0, long long nM0,
    const void* A0, long long nA0, const void* Wa, long long nWa,
    const void* lamb, const void* Larr, const void* L2arr,
    const void* parr, const void* alarr, const void* tauarr,
    const void* Hp, const void* Wp, int N, int* flags)
{
    if (threadIdx.x != 0 || blockIdx.x != 0) return;
    const void* rnd[4] = {X, M0, A0, Wa};
    long long cnt[4] = {nX, nM0, nA0, nWa};
    for (int t = 0; t < 4; t++) {
        const bf16* pb = (const bf16*)rnd[t];
        long long stride = cnt[t] / 128; if (stride < 1) stride = 1;
        int ok = 1;
        for (int s = 0; s < 128; s++) {
            long long idx = (long long)s * stride;
            if (idx >= cnt[t]) break;
            float v = b2f(pb[idx]);
            if (!(v > -100.f && v < 100.f)) { ok = 0; break; }  // NaN fails too
        }
        flags[t] = ok ? 0 : 1;   // 0 = bf16, 1 = f32
    }
    const void* cst[6] = {lamb, Larr, L2arr, parr, alarr, tauarr};
    for (int t = 0; t < 6; t++) {
        const unsigned short* u = (const unsigned short*)cst[t];
        flags[4 + t] = (u[0] == u[1]) ? 0 : 1;
    }
    int dims[2];
    const void* dp[2] = {Hp, Wp};
    for (int t = 0; t < 2; t++) {
        int d = -1;
        int c = ((const int*)dp[t])[0];
        if (c >= 1 && c <= N && N % c == 0) d = c;
        if (d < 0) {
            float f = ((const float*)dp[t])[0];
            int cf = (int)(f + 0.5f);
            if (f >= 1.f && f <= (float)N && cf >= 1 && N % cf == 0) d = cf;
        }
        if (d < 0) {
            float g = b2f(((const bf16*)dp[t])[0]);
            int cg = (int)(g + 0.5f);
            if (g >= 1.f && g <= (float)N && cg >= 1 && N % cg == 0) d = cg;
        }
        if (d < 0) { d = 1; while ((long long)d * d < N) d <<= 1; }
        dims[t] = d;
    }
    if ((long long)dims[0] * dims[1] != N) dims[1] = N / dims[0];
    flags[10] = dims[0];
    flags[11] = dims[1];
}

// ---------------------------------------------------------------------------
template <typename T>
__global__ void __launch_bounds__(256) k_init(
    const void* __restrict__ A0, const void* __restrict__ M0,
    T* __restrict__ A1, float* __restrict__ Mbuf,
    int N, int MRtot, const int* __restrict__ flags)
{
    int n = blockIdx.x * blockDim.x + threadIdx.x;
    int fA = flags[2], fM = flags[1];
    if (n < N) {
#pragma unroll
        for (int r = 0; r < RR; r++)
            stA(A1, (long long)r * N + n, ldf(A0, (long long)n * RR + r, fA));
    }
    if (n < MRtot) Mbuf[n] = ldf(M0, n, fM);
}

// ---------------------------------------------------------------------------
__global__ void k_pre(
    const void* __restrict__ Wa, const void* __restrict__ lambd,
    const void* __restrict__ Larr, const void* __restrict__ L2arr,
    const void* __restrict__ parr, const void* __restrict__ alarr,
    const void* __restrict__ tauarr, int k,
    const float* __restrict__ Mbuf,
    float* __restrict__ Wf, float* __restrict__ WM,
    float* __restrict__ cst_tau, float* __restrict__ cst_plam,
    float* __restrict__ G1, float* __restrict__ G2,
    float* __restrict__ sc, int bands, const int* __restrict__ flags)
{
    int tid = threadIdx.x;
    int fW = flags[3];
    for (int i = tid; i < bands * RR; i += blockDim.x)
        Wf[i] = ldf(Wa, (long long)k * bands * RR + i, fW);
    for (int i = tid; i < RR * RR; i += blockDim.x) G1[i] = 0.f;
    for (int i = tid; i < bands * RR; i += blockDim.x) G2[i] = 0.f;
    if (tid == 0) {
        float Lk  = ldf(Larr,  k, flags[5]);
        float al  = ldf(alarr, k, flags[8]);
        float pk  = ldf(parr,  k, flags[7]);
        float ta  = ldf(tauarr,k, flags[9]);
        float L2k = ldf(L2arr, k, flags[6]);
        float lmb = (al != 0.f) ? 2.f * ta / al : 0.f;
        sc[0] = Lk; sc[1] = al; sc[2] = pk; sc[3] = lmb;
        sc[4] = (lmb > 1e-30f) ? 1.f / (8.f * lmb) : 0.f;
        sc[5] = L2k;
    }
    if (tid < RR) {
        float pk  = ldf(parr, k, flags[7]);
        float lam = ldf(lambd, (long long)k * RR + tid, flags[4]);
        float e1 = 1.f / (2.f - pk);
        float e2 = (pk - 1.f) / (2.f - pk);
        float t = powf(2.f * (1.f - pk) * lam, e1)
                + pk * lam * powf(2.f * lam * (1.f - pk), e2);
        cst_tau[tid]  = t;
        cst_plam[tid] = pk * lam;
    }
    __syncthreads();
    if (tid < RR * RR) {
        int r = tid / RR, r2 = tid % RR;
        float s = 0.f;
        for (int b = 0; b < bands; b++) s += Wf[b * RR + r] * Mbuf[b * RR + r2];
        WM[tid] = s;
    }
}

// ---------------------------------------------------------------------------
// update_A fused per pixel. B recomputed in-register from A1 (exact formula);
// at k==0 (first=1), B = A bitwise per reference init.
template <typename T>
__global__ void __launch_bounds__(256) k_updateA(
    const void* __restrict__ X, const T* __restrict__ A1,
    const float* __restrict__ Wf, const float* __restrict__ WM,
    const float* __restrict__ cst_tau, const float* __restrict__ cst_plam,
    const float* __restrict__ sc,
    T* __restrict__ A2, int N, int bands, const int* __restrict__ flags,
    int first)
{
    int n = blockIdx.x * blockDim.x + threadIdx.x;
    if (n >= N) return;
    float a[RR], bv[RR], wx[RR];
#pragma unroll
    for (int r = 0; r < RR; r++) {
        a[r] = ldA(A1, (long long)r * N + n);
        wx[r] = 0.f;
    }
    if (first) {
#pragma unroll
        for (int r = 0; r < RR; r++) bv[r] = a[r];
    } else {
        float sb = 0.f;
#pragma unroll
        for (int r = 0; r < RR; r++) { float rl = fmaxf(a[r], 0.f); bv[r] = rl; sb += rl; }
        float invb = 1.f / (sb + 1e-4f);
#pragma unroll
        for (int r = 0; r < RR; r++) bv[r] *= invb;
    }
    if (flags[0]) {
        const float* Xf = (const float*)X;
        for (int b = 0; b < bands; b++) {
            float x = Xf[(long long)b * N + n];
#pragma unroll
            for (int r = 0; r < RR; r++) wx[r] = fmaf(Wf[b * RR + r], x, wx[r]);
        }
    } else {
        const bf16* Xb = (const bf16*)X;
        for (int b = 0; b < bands; b++) {
            float x = b2f(Xb[(long long)b * N + n]);
#pragma unroll
            for (int r = 0; r < RR; r++) wx[r] = fmaf(Wf[b * RR + r], x, wx[r]);
        }
    }
    float Lk = sc[0], al = sc[1], pk = sc[2];
    float o[RR];
    float s = 0.f;
#pragma unroll
    for (int r = 0; r < RR; r++) {
        float g = al * (a[r] - bv[r]) - wx[r];
#pragma unroll
        for (int r2 = 0; r2 < RR; r2++) g = fmaf(WM[r * RR + r2], a[r2], g);
        float v = a[r] - Lk * g;
        float t = 0.f;
        if (v > cst_tau[r]) t = v - cst_plam[r] * powf(v, pk - 1.f);
        t = fminf(t, 1.f);
        t = fmaxf(t, 0.f);
        o[r] = t;
        s += t;
    }
    float inv = 1.f / (s + 1e-4f);
#pragma unroll
    for (int r = 0; r < RR; r++) stA(A2, (long long)r * N + n, o[r] * inv);
}

// ---------------------------------------------------------------------------
// prox_TV per pixel per channel (raw prox output; B derived on the fly later).
template <typename T>
__global__ void __launch_bounds__(256) k_prox(
    const T* __restrict__ Ain, T* __restrict__ Aout,
    const float* __restrict__ sc, const int* __restrict__ flags, int N)
{
    int n = blockIdx.x * blockDim.x + threadIdx.x;
    if (n >= N) return;
    int H = flags[10], W = flags[11];
    int i = n / W, j = n % W;
    float lmb  = sc[3];
    float inv8 = sc[4];
#pragma unroll
    for (int r = 0; r < RR; r++) {
        const T* img = Ain + (long long)r * N;
        float c   = ldA(img, n);
        float dwn = (i < H - 1) ? ldA(img, n + W) : c;
        float rgt = (j < W - 1) ? ldA(img, n + 1) : c;
        float rr0 = (c - dwn) * inv8;
        float ss0 = (c - rgt) * inv8;
        float w0 = fmaxf(1.f, sqrtf(rr0 * rr0 + ss0 * ss0 + 1e-8f));
        float rn00 = rr0 / w0, sn00 = ss0 / w0;
        float rnU = 0.f;
        if (i > 0) {
            float cu = ldA(img, n - W);
            float ru = (j < W - 1) ? ldA(img, n - W + 1) : cu;
            float rru = (cu - c) * inv8;
            float ssu = (cu - ru) * inv8;
            float wu = fmaxf(1.f, sqrtf(rru * rru + ssu * ssu + 1e-8f));
            rnU = rru / wu;
        }
        float snL = 0.f;
        if (j > 0) {
            float cl = ldA(img, n - 1);
            float dl = (i < H - 1) ? ldA(img, n + W - 1) : cl;
            float rrl = (cl - dl) * inv8;
            float ssl = (cl - c) * inv8;
            float wl = fmaxf(1.f, sqrtf(rrl * rrl + ssl * ssl + 1e-8f));
            snL = ssl / wl;
        }
        float div = rn00 - rnU + sn00 - snL;
        stA(Aout, (long long)r * N + n, c - lmb * div);
    }
}

// ---------------------------------------------------------------------------
template <typename T>
__global__ void __launch_bounds__(256) k_g1(
    const T* __restrict__ A, float* __restrict__ G1, int N)
{
    float acc[RR][RR];
#pragma unroll
    for (int i = 0; i < RR; i++)
#pragma unroll
        for (int j = 0; j < RR; j++) acc[i][j] = 0.f;
    int stride = gridDim.x * blockDim.x;
    for (int n = blockIdx.x * blockDim.x + threadIdx.x; n < N; n += stride) {
        float a[RR];
#pragma unroll
        for (int r = 0; r < RR; r++) a[r] = ldA(A, (long long)r * N + n);
#pragma unroll
        for (int i = 0; i < RR; i++)
#pragma unroll
            for (int j = 0; j < RR; j++) acc[i][j] = fmaf(a[i], a[j], acc[i][j]);
    }
#pragma unroll
    for (int i = 0; i < RR; i++)
#pragma unroll
        for (int j = 0; j < RR; j++) {
            float v = acc[i][j];
            for (int off = 32; off; off >>= 1) v += __shfl_xor(v, off, 64);
            if ((threadIdx.x & 63) == 0) atomicAdd(&G1[i * RR + j], v);
        }
}

// ---------------------------------------------------------------------------
template <typename T>
__global__ void __launch_bounds__(64) k_g2(
    const void* __restrict__ X, const T* __restrict__ A,
    float* __restrict__ G2, int N, int bands, int bPerGroup,
    const int* __restrict__ flags)
{
    const int TT = 8;
    int lane = threadIdx.x;
    int n0 = blockIdx.x * (64 * TT);
    int b0 = blockIdx.y * bPerGroup;
    int bend = b0 + bPerGroup;
    if (bend > bands) bend = bands;
    int xf = flags[0];
    float areg[RR][TT];
#pragma unroll
    for (int r = 0; r < RR; r++)
#pragma unroll
        for (int t = 0; t < TT; t++) {
            int idx = n0 + lane + 64 * t;
            areg[r][t] = (idx < N) ? ldA(A, (long long)r * N + idx) : 0.f;
        }
    for (int b = b0; b < bend; b++) {
        float acc[RR];
#pragma unroll
        for (int r = 0; r < RR; r++) acc[r] = 0.f;
        if (xf) {
            const float* Xf = (const float*)X;
#pragma unroll
            for (int t = 0; t < TT; t++) {
                int idx = n0 + lane + 64 * t;
                float x = (idx < N) ? Xf[(long long)b * N + idx] : 0.f;
#pragma unroll
                for (int r = 0; r < RR; r++) acc[r] = fmaf(x, areg[r][t], acc[r]);
            }
        } else {
            const bf16* Xb = (const bf16*)X;
#pragma unroll
            for (int t = 0; t < TT; t++) {
                int idx = n0 + lane + 64 * t;
                float x = (idx < N) ? b2f(Xb[(long long)b * N + idx]) : 0.f;
#pragma unroll
                for (int r = 0; r < RR; r++) acc[r] = fmaf(x, areg[r][t], acc[r]);
            }
        }
#pragma unroll
        for (int r = 0; r < RR; r++) {
            float v = acc[r];
            for (int off = 32; off; off >>= 1) v += __shfl_xor(v, off, 64);
            if (lane == 0) atomicAdd(&G2[b * RR + r], v);
        }
    }
}

// ---------------------------------------------------------------------------
__global__ void __launch_bounds__(256) k_updateM(
    float* __restrict__ Mbuf, const float* __restrict__ G1,
    const float* __restrict__ G2, const float* __restrict__ sc, int bands)
{
    extern __shared__ float smem[];
    float* Ms  = smem;
    float* G1s = smem + bands * RR;
    int tid = threadIdx.x;
    for (int i = tid; i < bands * RR; i += 256) Ms[i] = Mbuf[i];
    for (int i = tid; i < RR * RR; i += 256) G1s[i] = G1[i];
    __syncthreads();
    float L2k = sc[5];
    for (int i = tid; i < bands * RR; i += 256) {
        int b = i >> 3, r = i & 7;
        float g = -G2[i];
#pragma unroll
        for (int r2 = 0; r2 < RR; r2++) g = fmaf(Ms[b * RR + r2], G1s[r2 * RR + r], g);
        Mbuf[i] = fmaxf(Ms[i] - L2k * g, 0.f);
    }
}

// ---------------------------------------------------------------------------
// pack output: [M | A] in the dtype of X (flags[0]: 1=f32, 0=bf16).
template <typename T>
__global__ void __launch_bounds__(256) k_out(
    const float* __restrict__ Mbuf, const T* __restrict__ A1,
    void* __restrict__ out, int MR, int RN, const int* __restrict__ flags)
{
    int i = blockIdx.x * blockDim.x + threadIdx.x;
    if (flags[0]) {
        float* o = (float*)out;
        if (i < MR) o[i] = Mbuf[i];
        if (i < RN) o[MR + i] = ldA(A1, i);
    } else {
        bf16* o = (bf16*)out;
        if (i < MR) o[i] = __float2bfloat16(Mbuf[i]);
        if (i < RN) o[MR + i] = __float2bfloat16(ldA(A1, i));
    }
}

// ---------------------------------------------------------------------------
template <typename T>
static void run_all(const void* X, const void* M0, const void* A0, const void* Wa,
                    const void* lambd, const void* Larr, const void* L2arr,
                    const void* parr, const void* alarr, const void* tauarr,
                    T* A1, T* A2, float* Mbuf, float* Wf, float* WM,
                    float* G1, float* G2, float* cst_tau, float* cst_plam,
                    float* sc, int* flags, void* out,
                    int N, int bands, int Rr, int K, hipStream_t stream)
{
    int nb = (N + 255) / 256;
    k_init<T><<<nb, 256, 0, stream>>>(A0, M0, A1, Mbuf, N, bands * Rr, flags);
    int bpg = (bands + 15) / 16;
    for (int k = 0; k < K; k++) {
        k_pre<<<1, 256, 0, stream>>>(Wa, lambd, Larr, L2arr, parr, alarr, tauarr, k,
                                     Mbuf, Wf, WM, cst_tau, cst_plam, G1, G2, sc,
                                     bands, flags);
        k_updateA<T><<<nb, 256, 0, stream>>>(X, A1, Wf, WM, cst_tau, cst_plam, sc,
                                             A2, N, bands, flags, (k == 0) ? 1 : 0);
        k_prox<T><<<nb, 256, 0, stream>>>(A2, A1, sc, flags, N);
        k_g1<T><<<64, 256, 0, stream>>>(A1, G1, N);
        dim3 g2grid((N + 511) / 512, 16);
        k_g2<T><<<g2grid, 64, 0, stream>>>(X, A1, G2, N, bands, bpg, flags);
        k_updateM<<<1, 256, (bands * Rr + 64) * sizeof(float), stream>>>(Mbuf, G1, G2, sc, bands);
    }
    k_out<T><<<((size_t)N * Rr + 255) / 256, 256, 0, stream>>>(Mbuf, A1, out, bands * Rr, N * Rr, flags);
}

// ---------------------------------------------------------------------------
extern "C" void kernel_launch(void* const* d_in, const int* in_sizes, int n_in,
                              void* d_out, int out_size, void* d_ws, size_t ws_size,
                              hipStream_t stream)
{
    const void* X      = d_in[0];
    const void* M0     = d_in[1];
    const void* A0     = d_in[2];
    const void* Wa     = d_in[3];
    const void* lambd  = d_in[4];
    const void* Larr   = d_in[5];
    const void* L2arr  = d_in[6];
    const void* parr   = d_in[7];
    const void* alarr  = d_in[8];
    const void* tauarr = d_in[9];
    const void* Hp     = d_in[10];
    const void* Wp     = d_in[11];

    int K = in_sizes[5];
    long long s0 = in_sizes[0], s1 = in_sizes[1], s2 = in_sizes[2];
    int Rr = (int)llround(sqrt((double)(s1 * s2) / (double)s0));  // == 8
    int bands = (int)(s1 / Rr);
    int N = (int)(s2 / Rr);
    size_t NR = (size_t)N * Rr;

    // --- workspace layout: ALL small state FIRST ---
    float* wsf = (float*)d_ws;
    int*   flags    = (int*)wsf;            // 16 ints
    float* sc       = wsf + 16;             // 8
    float* Mbuf     = wsf + 24;             // bands*Rr
    float* Wf       = Mbuf + bands * Rr;    // bands*Rr
    float* WM       = Wf + bands * Rr;      // 64
    float* G1       = WM + 64;              // 64
    float* G2       = G1 + 64;              // bands*Rr
    float* cst_tau  = G2 + bands * Rr;      // 8
    float* cst_plam = cst_tau + 8;          // 8
    size_t smallEnd = 24 + 3 * (size_t)bands * Rr + 64 + 64 + 16;
    size_t Aoff = (smallEnd + 1023) & ~(size_t)1023;

    size_t need32 = (Aoff + 2 * NR) * sizeof(float);

    k_probe<<<1, 64, 0, stream>>>(X, s0, M0, s1, A0, s2, Wa, (long long)in_sizes[3],
                                  lambd, Larr, L2arr, parr, alarr, tauarr,
                                  Hp, Wp, N, flags);

    if (ws_size >= need32) {
        float* A1 = wsf + Aoff;
        float* A2 = A1 + NR;
        run_all<float>(X, M0, A0, Wa, lambd, Larr, L2arr, parr, alarr, tauarr,
                       A1, A2, Mbuf, Wf, WM, G1, G2, cst_tau, cst_plam, sc, flags,
                       d_out, N, bands, Rr, K, stream);
    } else {
        bf16* A1 = (bf16*)(wsf + Aoff);
        bf16* A2 = A1 + NR;
        run_all<bf16>(X, M0, A0, Wa, lambd, Larr, L2arr, parr, alarr, tauarr,
                      A1, A2, Mbuf, Wf, WM, G1, G2, cst_tau, cst_plam, sc, flags,
                      d_out, N, bands, Rr, K, stream);
    }
}

// Round 5
// 2322.468 us; speedup vs baseline: 1.5943x; 1.5943x over previous
//
#include <hip/hip_runtime.h>
#include <hip/hip_bf16.h>
#include <cmath>

typedef __hip_bfloat16 bf16;

__device__ __forceinline__ float b2f(bf16 x) { return __bfloat162float(x); }
__device__ __forceinline__ float bfu(unsigned short s) {
    unsigned int t = ((unsigned int)s) << 16; float f;
    __builtin_memcpy(&f, &t, 4); return f;
}
__device__ __forceinline__ float ldf(const void* p, long long i, int f32) {
    return f32 ? ((const float*)p)[i] : b2f(((const bf16*)p)[i]);
}
__device__ __forceinline__ float ldA(const float* p, long long i) { return p[i]; }
__device__ __forceinline__ float ldA(const bf16* p, long long i)  { return b2f(p[i]); }
__device__ __forceinline__ void  stA(float* p, long long i, float v) { p[i] = v; }
__device__ __forceinline__ void  stA(bf16* p, long long i, float v)  { p[i] = __float2bfloat16(v); }

// 8-wide vector loads; callers guarantee 16B alignment
__device__ __forceinline__ void ld8(const float* p, float o[8]) {
    float4 u0 = ((const float4*)p)[0], u1 = ((const float4*)p)[1];
    o[0]=u0.x; o[1]=u0.y; o[2]=u0.z; o[3]=u0.w;
    o[4]=u1.x; o[5]=u1.y; o[6]=u1.z; o[7]=u1.w;
}
__device__ __forceinline__ void ld8(const bf16* p, float o[8]) {
    uint4 u = *(const uint4*)p;
    o[0]=bfu(u.x&0xffff); o[1]=bfu((unsigned short)(u.x>>16));
    o[2]=bfu(u.y&0xffff); o[3]=bfu((unsigned short)(u.y>>16));
    o[4]=bfu(u.z&0xffff); o[5]=bfu((unsigned short)(u.z>>16));
    o[6]=bfu(u.w&0xffff); o[7]=bfu((unsigned short)(u.w>>16));
}

#define RR 8  // endmembers

// flags: [0]=X f32? [1]=M0 [2]=A0 [3]=Wa [4]=lambd [5]=L [6]=L2 [7]=p
//        [8]=alpha [9]=tau [10]=H [11]=W
// sc: [0]=Lk [1]=alpha [2]=pk [3]=lmbda(prox) [4]=inv8 [5]=L2k

// ---------------------------------------------------------------------------
__global__ void k_probe(
    const void* X, long long nX, const void* M0, long long nM0,
    const void* A0, long long nA0, const void* Wa, long long nWa,
    const void* lamb, const void* Larr, const void* L2arr,
    const void* parr, const void* alarr, const void* tauarr,
    const void* Hp, const void* Wp, int N, int* flags)
{
    if (threadIdx.x != 0 || blockIdx.x != 0) return;
    const void* rnd[4] = {X, M0, A0, Wa};
    long long cnt[4] = {nX, nM0, nA0, nWa};
    for (int t = 0; t < 4; t++) {
        const bf16* pb = (const bf16*)rnd[t];
        long long stride = cnt[t] / 128; if (stride < 1) stride = 1;
        int ok = 1;
        for (int s = 0; s < 128; s++) {
            long long idx = (long long)s * stride;
            if (idx >= cnt[t]) break;
            float v = b2f(pb[idx]);
            if (!(v > -100.f && v < 100.f)) { ok = 0; break; }
        }
        flags[t] = ok ? 0 : 1;   // 0 = bf16, 1 = f32
    }
    const void* cst[6] = {lamb, Larr, L2arr, parr, alarr, tauarr};
    for (int t = 0; t < 6; t++) {
        const unsigned short* u = (const unsigned short*)cst[t];
        flags[4 + t] = (u[0] == u[1]) ? 0 : 1;
    }
    int dims[2];
    const void* dp[2] = {Hp, Wp};
    for (int t = 0; t < 2; t++) {
        int d = -1;
        int c = ((const int*)dp[t])[0];
        if (c >= 1 && c <= N && N % c == 0) d = c;
        if (d < 0) {
            float f = ((const float*)dp[t])[0];
            int cf = (int)(f + 0.5f);
            if (f >= 1.f && f <= (float)N && cf >= 1 && N % cf == 0) d = cf;
        }
        if (d < 0) {
            float g = b2f(((const bf16*)dp[t])[0]);
            int cg = (int)(g + 0.5f);
            if (g >= 1.f && g <= (float)N && cg >= 1 && N % cg == 0) d = cg;
        }
        if (d < 0) { d = 1; while ((long long)d * d < N) d <<= 1; }
        dims[t] = d;
    }
    if ((long long)dims[0] * dims[1] != N) dims[1] = N / dims[0];
    flags[10] = dims[0];
    flags[11] = dims[1];
}

// ---------------------------------------------------------------------------
template <typename T>
__global__ void __launch_bounds__(256) k_init(
    const void* __restrict__ A0, const void* __restrict__ M0,
    T* __restrict__ A1, float* __restrict__ Mbuf,
    int N, int MRtot, const int* __restrict__ flags)
{
    int n = blockIdx.x * blockDim.x + threadIdx.x;
    int fA = flags[2], fM = flags[1];
    if (n < N) {
#pragma unroll
        for (int r = 0; r < RR; r++)
            stA(A1, (long long)r * N + n, ldf(A0, (long long)n * RR + r, fA));
    }
    if (n < MRtot) Mbuf[n] = ldf(M0, n, fM);
}

// ---------------------------------------------------------------------------
__global__ void k_pre(
    const void* __restrict__ Wa, const void* __restrict__ lambd,
    const void* __restrict__ Larr, const void* __restrict__ L2arr,
    const void* __restrict__ parr, const void* __restrict__ alarr,
    const void* __restrict__ tauarr, int k,
    const float* __restrict__ Mbuf,
    float* __restrict__ Wf, float* __restrict__ WM,
    float* __restrict__ cst_tau, float* __restrict__ cst_plam,
    float* __restrict__ sc, int bands, const int* __restrict__ flags)
{
    int tid = threadIdx.x;
    int fW = flags[3];
    for (int i = tid; i < bands * RR; i += blockDim.x)
        Wf[i] = ldf(Wa, (long long)k * bands * RR + i, fW);
    if (tid == 0) {
        float Lk  = ldf(Larr,  k, flags[5]);
        float al  = ldf(alarr, k, flags[8]);
        float pk  = ldf(parr,  k, flags[7]);
        float ta  = ldf(tauarr,k, flags[9]);
        float L2k = ldf(L2arr, k, flags[6]);
        float lmb = (al != 0.f) ? 2.f * ta / al : 0.f;
        sc[0] = Lk; sc[1] = al; sc[2] = pk; sc[3] = lmb;
        sc[4] = (lmb > 1e-30f) ? 1.f / (8.f * lmb) : 0.f;
        sc[5] = L2k;
    }
    if (tid < RR) {
        float pk  = ldf(parr, k, flags[7]);
        float lam = ldf(lambd, (long long)k * RR + tid, flags[4]);
        float e1 = 1.f / (2.f - pk);
        float e2 = (pk - 1.f) / (2.f - pk);
        float t = powf(2.f * (1.f - pk) * lam, e1)
                + pk * lam * powf(2.f * lam * (1.f - pk), e2);
        cst_tau[tid]  = t;
        cst_plam[tid] = pk * lam;
    }
    __syncthreads();
    if (tid < RR * RR) {
        int r = tid / RR, r2 = tid % RR;
        float s = 0.f;
        for (int b = 0; b < bands; b++) s += Wf[b * RR + r] * Mbuf[b * RR + r2];
        WM[tid] = s;
    }
}

// ---------------------------------------------------------------------------
// update_A, 2 pixels per thread, packed bf16x2 X loads.
template <typename T>
__global__ void __launch_bounds__(256) k_updateA2(
    const void* __restrict__ X, const T* __restrict__ A1,
    const float* __restrict__ Wf, const float* __restrict__ WM,
    const float* __restrict__ cst_tau, const float* __restrict__ cst_plam,
    const float* __restrict__ sc,
    T* __restrict__ A2, long long N, int bands, const int* __restrict__ flags,
    int first)
{
    long long N2 = (N + 1) >> 1;
    long long g = (long long)blockIdx.x * 256 + threadIdx.x;
    if (g >= N2) return;
    long long n = g * 2;
    int two = (n + 1 < N) ? 1 : 0;
    int xf = flags[0];
    int packed = (!xf) && two && ((N & 1LL) == 0);

    float a[RR][2], bv[RR][2], wx[RR][2];
#pragma unroll
    for (int r = 0; r < RR; r++) {
        a[r][0] = ldA(A1, (long long)r * N + n);
        a[r][1] = two ? ldA(A1, (long long)r * N + n + 1) : 0.f;
        wx[r][0] = wx[r][1] = 0.f;
    }
    if (first) {
#pragma unroll
        for (int r = 0; r < RR; r++) { bv[r][0] = a[r][0]; bv[r][1] = a[r][1]; }
    } else {
#pragma unroll
        for (int c = 0; c < 2; c++) {
            float sb = 0.f;
#pragma unroll
            for (int r = 0; r < RR; r++) { float rl = fmaxf(a[r][c], 0.f); bv[r][c] = rl; sb += rl; }
            float invb = 1.f / (sb + 1e-4f);
#pragma unroll
            for (int r = 0; r < RR; r++) bv[r][c] *= invb;
        }
    }

    if (packed) {
        const unsigned int* Xu = (const unsigned int*)X;
        long long half = N >> 1;
        for (int b = 0; b < bands; b++) {
            unsigned int u = Xu[(long long)b * half + g];
            float x0 = bfu((unsigned short)(u & 0xffff));
            float x1 = bfu((unsigned short)(u >> 16));
#pragma unroll
            for (int r = 0; r < RR; r++) {
                float w = Wf[b * RR + r];
                wx[r][0] = fmaf(w, x0, wx[r][0]);
                wx[r][1] = fmaf(w, x1, wx[r][1]);
            }
        }
    } else {
        for (int b = 0; b < bands; b++) {
            float x0 = ldf(X, (long long)b * N + n, xf);
            float x1 = two ? ldf(X, (long long)b * N + n + 1, xf) : 0.f;
#pragma unroll
            for (int r = 0; r < RR; r++) {
                float w = Wf[b * RR + r];
                wx[r][0] = fmaf(w, x0, wx[r][0]);
                wx[r][1] = fmaf(w, x1, wx[r][1]);
            }
        }
    }

    float Lk = sc[0], al = sc[1], pk = sc[2];
#pragma unroll
    for (int c = 0; c < 2; c++) {
        if (c == 1 && !two) break;
        float o[RR];
        float s = 0.f;
#pragma unroll
        for (int r = 0; r < RR; r++) {
            float gg = al * (a[r][c] - bv[r][c]) - wx[r][c];
#pragma unroll
            for (int r2 = 0; r2 < RR; r2++) gg = fmaf(WM[r * RR + r2], a[r2][c], gg);
            float v = a[r][c] - Lk * gg;
            float t = 0.f;
            if (v > cst_tau[r]) t = v - cst_plam[r] * powf(v, pk - 1.f);
            t = fminf(t, 1.f);
            t = fmaxf(t, 0.f);
            o[r] = t;
            s += t;
        }
        float inv = 1.f / (s + 1e-4f);
#pragma unroll
        for (int r = 0; r < RR; r++) stA(A2, (long long)r * N + n + c, o[r] * inv);
    }
}

// ---------------------------------------------------------------------------
// prox_TV per pixel per channel (raw prox output; B derived on the fly later).
template <typename T>
__global__ void __launch_bounds__(256) k_prox(
    const T* __restrict__ Ain, T* __restrict__ Aout,
    const float* __restrict__ sc, const int* __restrict__ flags, int N)
{
    int n = blockIdx.x * blockDim.x + threadIdx.x;
    if (n >= N) return;
    int H = flags[10], W = flags[11];
    int i = n / W, j = n % W;
    float lmb  = sc[3];
    float inv8 = sc[4];
#pragma unroll
    for (int r = 0; r < RR; r++) {
        const T* img = Ain + (long long)r * N;
        float c   = ldA(img, n);
        float dwn = (i < H - 1) ? ldA(img, n + W) : c;
        float rgt = (j < W - 1) ? ldA(img, n + 1) : c;
        float rr0 = (c - dwn) * inv8;
        float ss0 = (c - rgt) * inv8;
        float w0 = fmaxf(1.f, sqrtf(rr0 * rr0 + ss0 * ss0 + 1e-8f));
        float rn00 = rr0 / w0, sn00 = ss0 / w0;
        float rnU = 0.f;
        if (i > 0) {
            float cu = ldA(img, n - W);
            float ru = (j < W - 1) ? ldA(img, n - W + 1) : cu;
            float rru = (cu - c) * inv8;
            float ssu = (cu - ru) * inv8;
            float wu = fmaxf(1.f, sqrtf(rru * rru + ssu * ssu + 1e-8f));
            rnU = rru / wu;
        }
        float snL = 0.f;
        if (j > 0) {
            float cl = ldA(img, n - 1);
            float dl = (i < H - 1) ? ldA(img, n + W - 1) : cl;
            float rrl = (cl - dl) * inv8;
            float ssl = (cl - c) * inv8;
            float wl = fmaxf(1.f, sqrtf(rrl * rrl + ssl * ssl + 1e-8f));
            snL = ssl / wl;
        }
        float div = rn00 - rnU + sn00 - snL;
        stA(Aout, (long long)r * N + n, c - lmb * div);
    }
}

// ---------------------------------------------------------------------------
// G2 stage 1: per-wave partial rows of [bands x 8 | G1 64] into scratch.
// wave = 512 px; A fragment in registers; bands in groups of 8 with 64
// register accumulators; wave-local LDS transpose (swizzled, <=2-way banks);
// plain stores, no atomics. G1 = A A^T folded in as a final group.
template <typename T>
__global__ void __launch_bounds__(256) k_g2s1(
    const void* __restrict__ X, const T* __restrict__ A,
    float* __restrict__ scr, long long N, int bands, int groups,
    const int* __restrict__ flags)
{
    __shared__ float lds[4 * 64 * 64];
    int wave = threadIdx.x >> 6, lane = threadIdx.x & 63;
    float* wl = lds + wave * 4096;
    long long wId = (long long)blockIdx.x * 4 + wave;
    long long n0 = wId * 512;
    int xf = flags[0];
    int inb = (n0 + 512 <= N) && ((N & 7LL) == 0);

    float areg[8][8];
    if (inb) {
#pragma unroll
        for (int r = 0; r < 8; r++) ld8(A + (long long)r * N + n0 + lane * 8, areg[r]);
    } else {
#pragma unroll
        for (int r = 0; r < 8; r++)
#pragma unroll
            for (int t = 0; t < 8; t++) {
                long long idx = n0 + lane * 8 + t;
                areg[r][t] = (idx < N) ? ldA(A, (long long)r * N + idx) : 0.f;
            }
    }

    long long rowlen = (long long)groups * 64 + 64;
    float* out = scr + wId * rowlen;

    for (int g = 0; g < groups; g++) {
        float pacc[64];
#pragma unroll
        for (int k = 0; k < 64; k++) pacc[k] = 0.f;
#pragma unroll
        for (int bi = 0; bi < 8; bi++) {
            int b = g * 8 + bi;
            if (b < bands) {
                float x[8];
                if (!xf) {
                    const bf16* Xb = (const bf16*)X;
                    if (inb) ld8(Xb + (long long)b * N + n0 + lane * 8, x);
                    else {
#pragma unroll
                        for (int t = 0; t < 8; t++) {
                            long long idx = n0 + lane * 8 + t;
                            x[t] = (idx < N) ? b2f(Xb[(long long)b * N + idx]) : 0.f;
                        }
                    }
                } else {
                    const float* Xf = (const float*)X;
                    if (inb) ld8(Xf + (long long)b * N + n0 + lane * 8, x);
                    else {
#pragma unroll
                        for (int t = 0; t < 8; t++) {
                            long long idx = n0 + lane * 8 + t;
                            x[t] = (idx < N) ? Xf[(long long)b * N + idx] : 0.f;
                        }
                    }
                }
#pragma unroll
                for (int t = 0; t < 8; t++)
#pragma unroll
                    for (int r = 0; r < 8; r++)
                        pacc[bi * 8 + r] = fmaf(x[t], areg[r][t], pacc[bi * 8 + r]);
            }
        }
#pragma unroll
        for (int k = 0; k < 64; k++) wl[k * 64 + ((lane + k) & 63)] = pacc[k];
        float s = 0.f;
#pragma unroll
        for (int j = 0; j < 64; j++) s += wl[lane * 64 + ((lane + j) & 63)];
        out[(long long)g * 64 + lane] = s;
    }
    // G1 group
    {
        float pacc[64];
#pragma unroll
        for (int i = 0; i < 8; i++)
#pragma unroll
            for (int j2 = 0; j2 < 8; j2++) {
                float s = 0.f;
#pragma unroll
                for (int t = 0; t < 8; t++) s = fmaf(areg[i][t], areg[j2][t], s);
                pacc[i * 8 + j2] = s;
            }
#pragma unroll
        for (int k = 0; k < 64; k++) wl[k * 64 + ((lane + k) & 63)] = pacc[k];
        float s = 0.f;
#pragma unroll
        for (int j = 0; j < 64; j++) s += wl[lane * 64 + ((lane + j) & 63)];
        out[(long long)groups * 64 + lane] = s;
    }
}

// ---------------------------------------------------------------------------
// G2 stage 2: sum partial rows -> G2 [MR], G1 [64]. Plain stores.
__global__ void __launch_bounds__(256) k_g2s2(
    const float* __restrict__ scr, float* __restrict__ G2, float* __restrict__ G1,
    int MR, int groups, long long nw)
{
    int j = blockIdx.x * 256 + threadIdx.x;
    if (j >= MR + 64) return;
    long long rowlen = (long long)groups * 64 + 64;
    long long off = (j < MR) ? j : ((long long)groups * 64 + (j - MR));
    float s = 0.f;
    for (long long w = 0; w < nw; w++) s += scr[w * rowlen + off];
    if (j < MR) G2[j] = s; else G1[j - MR] = s;
}

// ---------------------------------------------------------------------------
__global__ void __launch_bounds__(256) k_updateM(
    float* __restrict__ Mbuf, const float* __restrict__ G1,
    const float* __restrict__ G2, const float* __restrict__ sc, int bands)
{
    extern __shared__ float smem[];
    float* Ms  = smem;
    float* G1s = smem + bands * RR;
    int tid = threadIdx.x;
    for (int i = tid; i < bands * RR; i += 256) Ms[i] = Mbuf[i];
    for (int i = tid; i < RR * RR; i += 256) G1s[i] = G1[i];
    __syncthreads();
    float L2k = sc[5];
    for (int i = tid; i < bands * RR; i += 256) {
        int b = i >> 3, r = i & 7;
        float g = -G2[i];
#pragma unroll
        for (int r2 = 0; r2 < RR; r2++) g = fmaf(Ms[b * RR + r2], G1s[r2 * RR + r], g);
        Mbuf[i] = fmaxf(Ms[i] - L2k * g, 0.f);
    }
}

// ---------------------------------------------------------------------------
template <typename T>
__global__ void __launch_bounds__(256) k_out(
    const float* __restrict__ Mbuf, const T* __restrict__ A1,
    void* __restrict__ out, int MR, int RN, const int* __restrict__ flags)
{
    int i = blockIdx.x * blockDim.x + threadIdx.x;
    if (flags[0]) {
        float* o = (float*)out;
        if (i < MR) o[i] = Mbuf[i];
        if (i < RN) o[MR + i] = ldA(A1, i);
    } else {
        bf16* o = (bf16*)out;
        if (i < MR) o[i] = __float2bfloat16(Mbuf[i]);
        if (i < RN) o[MR + i] = __float2bfloat16(ldA(A1, i));
    }
}

// ---------------------------------------------------------------------------
template <typename T>
static void run_all(const void* X, const void* M0, const void* A0, const void* Wa,
                    const void* lambd, const void* Larr, const void* L2arr,
                    const void* parr, const void* alarr, const void* tauarr,
                    T* A1, T* A2, float* scr, float* Mbuf, float* Wf, float* WM,
                    float* G1, float* G2, float* cst_tau, float* cst_plam,
                    float* sc, int* flags, void* out,
                    int N, int bands, int Rr, int K, hipStream_t stream)
{
    int nb = (N + 255) / 256;
    k_init<T><<<nb, 256, 0, stream>>>(A0, M0, A1, Mbuf, N, bands * Rr, flags);
    int groups = (bands + 7) / 8;
    int blocks1 = (N + 2047) / 2048;
    long long nw = (long long)blocks1 * 4;
    long long N2 = ((long long)N + 1) >> 1;
    int nbU = (int)((N2 + 255) / 256);
    int MR = bands * Rr;
    int nb2 = (MR + 64 + 255) / 256;
    for (int k = 0; k < K; k++) {
        k_pre<<<1, 256, 0, stream>>>(Wa, lambd, Larr, L2arr, parr, alarr, tauarr, k,
                                     Mbuf, Wf, WM, cst_tau, cst_plam, sc,
                                     bands, flags);
        k_updateA2<T><<<nbU, 256, 0, stream>>>(X, A1, Wf, WM, cst_tau, cst_plam, sc,
                                               A2, N, bands, flags, (k == 0) ? 1 : 0);
        k_prox<T><<<nb, 256, 0, stream>>>(A2, A1, sc, flags, N);
        k_g2s1<T><<<blocks1, 256, 0, stream>>>(X, A1, scr, N, bands, groups, flags);
        k_g2s2<<<nb2, 256, 0, stream>>>(scr, G2, G1, MR, groups, nw);
        k_updateM<<<1, 256, (bands * Rr + 64) * sizeof(float), stream>>>(Mbuf, G1, G2, sc, bands);
    }
    k_out<T><<<((size_t)N * Rr + 255) / 256, 256, 0, stream>>>(Mbuf, A1, out, bands * Rr, N * Rr, flags);
}

// ---------------------------------------------------------------------------
extern "C" void kernel_launch(void* const* d_in, const int* in_sizes, int n_in,
                              void* d_out, int out_size, void* d_ws, size_t ws_size,
                              hipStream_t stream)
{
    const void* X      = d_in[0];
    const void* M0     = d_in[1];
    const void* A0     = d_in[2];
    const void* Wa     = d_in[3];
    const void* lambd  = d_in[4];
    const void* Larr   = d_in[5];
    const void* L2arr  = d_in[6];
    const void* parr   = d_in[7];
    const void* alarr  = d_in[8];
    const void* tauarr = d_in[9];
    const void* Hp     = d_in[10];
    const void* Wp     = d_in[11];

    int K = in_sizes[5];
    long long s0 = in_sizes[0], s1 = in_sizes[1], s2 = in_sizes[2];
    int Rr = (int)llround(sqrt((double)(s1 * s2) / (double)s0));  // == 8
    int bands = (int)(s1 / Rr);
    int N = (int)(s2 / Rr);
    size_t NR = (size_t)N * Rr;

    // --- workspace layout: small state first, then A buffers, then scratch ---
    float* wsf = (float*)d_ws;
    int*   flags    = (int*)wsf;            // 16 ints
    float* sc       = wsf + 16;             // 8
    float* Mbuf     = wsf + 24;             // bands*Rr
    float* Wf       = Mbuf + bands * Rr;    // bands*Rr
    float* WM       = Wf + bands * Rr;      // 64
    float* G1       = WM + 64;              // 64
    float* G2       = G1 + 64;              // bands*Rr
    float* cst_tau  = G2 + bands * Rr;      // 8
    float* cst_plam = cst_tau + 8;          // 8
    size_t smallEnd = 24 + 3 * (size_t)bands * Rr + 64 + 64 + 16;
    size_t Aoff = (smallEnd + 1023) & ~(size_t)1023;

    int groups = (bands + 7) / 8;
    int blocks1 = (N + 2047) / 2048;
    size_t nw = (size_t)blocks1 * 4;
    size_t rowlen = (size_t)groups * 64 + 64;
    size_t scrElems = nw * rowlen;

    size_t need32 = (Aoff + 2 * NR + scrElems) * sizeof(float);
    size_t need16 = (Aoff + NR + scrElems) * sizeof(float);  // bf16 A buffers

    k_probe<<<1, 64, 0, stream>>>(X, s0, M0, s1, A0, s2, Wa, (long long)in_sizes[3],
                                  lambd, Larr, L2arr, parr, alarr, tauarr,
                                  Hp, Wp, N, flags);

    if (ws_size >= need32) {
        float* A1 = wsf + Aoff;
        float* A2 = A1 + NR;
        float* scr = A2 + NR;
        run_all<float>(X, M0, A0, Wa, lambd, Larr, L2arr, parr, alarr, tauarr,
                       A1, A2, scr, Mbuf, Wf, WM, G1, G2, cst_tau, cst_plam, sc, flags,
                       d_out, N, bands, Rr, K, stream);
    } else {
        bf16* A1 = (bf16*)(wsf + Aoff);
        bf16* A2 = A1 + NR;
        float* scr = wsf + Aoff + NR;   // 2*NR bf16 = NR floats
        run_all<bf16>(X, M0, A0, Wa, lambd, Larr, L2arr, parr, alarr, tauarr,
                      A1, A2, scr, Mbuf, Wf, WM, G1, G2, cst_tau, cst_plam, sc, flags,
                      d_out, N, bands, Rr, K, stream);
    }
}